// Round 17
// baseline (506.201 us; speedup 1.0000x reference)
//
#include <hip/hip_runtime.h>
#include <hip/hip_bf16.h>
#include <math.h>

// Problem constants (fixed by setup_inputs)
#define N_NODES   50000
#define N_EDGES   800000
#define N_REL     1000
#define DIM       128
#define DEPTH_L   2
#define OUT_STRIDE (DIM * (DEPTH_L + 1))   // 384

#define TANH0_BLOCKS  ((N_NODES * 32) / 256)          // 6250 (exact)
#define EINFO_BLOCKS  ((N_EDGES + 255) / 256)         // 3125 (exact)
#define PREP_BLOCKS   ((N_REL + 1 + 3) / 4)           // 251 (4 relations/block)
#define RP_BLOCKS     ((N_NODES + 1 + 255) / 256)     // 196

typedef _Float16 h2 __attribute__((ext_vector_type(2)));

#if defined(__has_builtin)
#if __has_builtin(__builtin_amdgcn_fdot2)
#define FDOT2(a, b, c) __builtin_amdgcn_fdot2((a), (b), (c), false)
#endif
#endif
#ifndef FDOT2
#define FDOT2(a, b, c) ((c) + (float)(a).x * (float)(b).x + (float)(a).y * (float)(b).y)
#endif

// fast tanh: (e^{2x}-1)/(e^{2x}+1), clamped so exp never overflows.
__device__ __forceinline__ float fast_tanh(float x) {
    float cx = fminf(fmaxf(x, -15.f), 15.f);
    float e = __expf(2.f * cx);
    return (e - 1.f) * __frcp_rn(e + 1.f);
}

// ---------------------------------------------------------------------------
// Kernel 1 (FUSED, partitioned by blockIdx):
//   blocks [0, PREP_BLOCKS): per-relation precompute, 4 relations/block.
//   blocks [PREP_BLOCKS, ..): CSR row pointers (binary search) + s0/s1 zero.
// ---------------------------------------------------------------------------
__global__ __launch_bounds__(256) void prep_kernel(
    const float* __restrict__ rel_emb,
    const float* __restrict__ attn_k,
    _Float16* __restrict__ rhat,
    float* __restrict__ er0, float* __restrict__ er1,
    const int* __restrict__ src, int* __restrict__ rp,
    float* __restrict__ s0, float* __restrict__ s1)
{
    if (blockIdx.x < PREP_BLOCKS) {
        int wid  = threadIdx.x >> 6;
        int lane = threadIdx.x & 63;
        int r = blockIdx.x * 4 + wid;
        if (r > N_REL) return;
        if (r == N_REL) {                   // zero row / unit exp slot
            rhat[(size_t)r * DIM + lane]      = (_Float16)0.f;
            rhat[(size_t)r * DIM + lane + 64] = (_Float16)0.f;
            if (lane == 0) { er0[N_REL] = 1.f; er1[N_REL] = 1.f; }
            return;
        }
        float v0 = rel_emb[r * DIM + lane];
        float v1 = rel_emb[r * DIM + lane + 64];
        float ss = v0 * v0 + v1 * v1;
        #pragma unroll
        for (int o = 32; o >= 1; o >>= 1) ss += __shfl_xor(ss, o);
        float inv = 1.0f / fmaxf(sqrtf(ss), 1e-12f);
        float t0 = v0 * inv, t1 = v1 * inv;
        rhat[(size_t)r * DIM + lane]      = (_Float16)t0;
        rhat[(size_t)r * DIM + lane + 64] = (_Float16)t1;
        #pragma unroll
        for (int l = 0; l < DEPTH_L; ++l) {
            float d = t0 * attn_k[l * DIM + lane] + t1 * attn_k[l * DIM + lane + 64];
            #pragma unroll
            for (int o = 32; o >= 1; o >>= 1) d += __shfl_xor(d, o);
            if (lane == 0) {
                if (l == 0) er0[r] = __expf(d); else er1[r] = __expf(d);
            }
        }
        return;
    }

    int n = (blockIdx.x - PREP_BLOCKS) * 256 + threadIdx.x;
    if (n > N_NODES) return;
    int lo = 0, hi = N_EDGES;
    while (lo < hi) {
        int mid = (lo + hi) >> 1;
        if (src[mid] < n) lo = mid + 1; else hi = mid;
    }
    rp[n] = lo;
    if (n < N_NODES) { s0[n] = 0.f; s1[n] = 0.f; }
}

// ---------------------------------------------------------------------------
// Kernel 2 (FUSED independent aux work, partitioned by blockIdx):
//   blocks [0, TANH0_BLOCKS): out[:,0:128] = tanh(features) + f16 mirror
//   blocks [TANH0_BLOCKS, ..): edge-parallel softmax denominator + einfo2
// ---------------------------------------------------------------------------
__global__ __launch_bounds__(256) void aux_fused_kernel(
    const float* __restrict__ feat, float* __restrict__ out,
    _Float16* __restrict__ fs0,
    const int* __restrict__ src, const int* __restrict__ dst,
    const int* __restrict__ relid, const float* __restrict__ rval,
    const float* __restrict__ er0, const float* __restrict__ er1,
    float* __restrict__ s0, float* __restrict__ s1,
    uint2* __restrict__ einfo2)
{
    if (blockIdx.x < TANH0_BLOCKS) {
        int i = blockIdx.x * 256 + threadIdx.x;      // exactly N*32 threads
        int n = i >> 5;
        int j = i & 31;
        float4 v = reinterpret_cast<const float4*>(feat + (size_t)n * DIM)[j];
        float4 o;
        o.x = fast_tanh(v.x); o.y = fast_tanh(v.y);
        o.z = fast_tanh(v.z); o.w = fast_tanh(v.w);
        reinterpret_cast<float4*>(out + (size_t)n * OUT_STRIDE)[j] = o;
        h2 p0; p0.x = (_Float16)o.x; p0.y = (_Float16)o.y;
        h2 p1; p1.x = (_Float16)o.z; p1.y = (_Float16)o.w;
        uint2 u;
        u.x = __builtin_bit_cast(unsigned, p0);
        u.y = __builtin_bit_cast(unsigned, p1);
        reinterpret_cast<uint2*>(fs0 + (size_t)n * DIM)[j] = u;
        return;
    }

    int e = (blockIdx.x - TANH0_BLOCKS) * 256 + threadIdx.x;
    if (e >= N_EDGES) return;
    int lane = threadIdx.x & 63;
    int sn = src[e];
    int r = (rval[e] == 0.f) ? N_REL : relid[e];
    float x0 = er0[r], x1 = er1[r];

    h2 ep; ep.x = (_Float16)x0; ep.y = (_Float16)x1;
    einfo2[e] = make_uint2((unsigned)dst[e] | ((unsigned)r << 16),
                           __builtin_bit_cast(unsigned, ep));

    // segmented inclusive scan over lanes with equal sn (src is sorted)
    #pragma unroll
    for (int off = 1; off < 64; off <<= 1) {
        float y0 = __shfl_up(x0, off);
        float y1 = __shfl_up(x1, off);
        int   sp = __shfl_up(sn, off);
        if (lane >= off && sp == sn) { x0 += y0; x1 += y1; }
    }
    int snext = __shfl_down(sn, 1);
    bool lastlane = (lane == 63) || (e == N_EDGES - 1) || (snext != sn);
    if (lastlane) {
        atomicAdd(&s0[sn], x0);
        atomicAdd(&s1[sn], x1);
    }
}

// ---------------------------------------------------------------------------
// Kernel 3 (per layer L): FUSED gather + reflect + accumulate, f16 inputs.
// MERGED-RANGE QUAD-NODE WAVES: one wave owns nodes 4k..4k+3 whose edges
// are CONTIGUOUS [rp[4k], rp[4k+4]) — one head (rp + TWO parallel upfront
// einfo wave-loads covering <=128 edges), ONE ~8-chunk pipeline. Chunk
// purity vs mids m1,m2,m3 is wave-uniform; straddling chunks (<=3/wave)
// take masked ACCs only into overlapped sets. Depth-2 pipeline +
// sched_barrier(0); exec-masked tail gathers (w=0). 8 lanes/edge.
// ---------------------------------------------------------------------------
template<int L>
__global__ __launch_bounds__(128) void layer_fused_kernel(
    const _Float16* __restrict__ fs_in,   // [N,128] f16
    float* __restrict__ fout,             // column block in d_out
    _Float16* __restrict__ fs_out,        // [N,128] f16 mirror (L==0 only)
    const uint2* __restrict__ einfo2,
    const int* __restrict__ rp,
    const float* __restrict__ s_l,        // [N] softmax denominators
    const _Float16* __restrict__ rhat)    // [(R+1),128] f16
{
    int wid  = threadIdx.x >> 6;
    int lane = threadIdx.x & 63;
    int wave = blockIdx.x * 2 + wid;
    int n0 = wave * 4;
    if (n0 >= N_NODES) return;            // N divisible by 4
    int start = rp[n0], m1 = rp[n0 + 1], m2 = rp[n0 + 2],
        m3 = rp[n0 + 3], end = rp[n0 + 4];

    float is0 = 1.0f / s_l[n0];           // safe: only multiplied for valid e
    float is1 = 1.0f / s_l[n0 + 1];
    float is2 = 1.0f / s_l[n0 + 2];
    float is3 = 1.0f / s_l[n0 + 3];

    int g = lane >> 3;      // edge slot within chunk (0..7)
    int q = lane & 7;       // dim group: dims [16q, 16q+16)
    const char* fbase = (const char*)fs_in + 32 * q;
    const char* tbase = (const char*)rhat  + 32 * q;
    int g0 = (lane >> 3) & 1, g1 = (lane >> 4) & 1, g2 = (lane >> 5) & 1;

    h2 aA[8], aB[8], aC[8], aD[8];
    #pragma unroll
    for (int i = 0; i < 8; ++i) {
        aA[i].x = (_Float16)0.f; aA[i].y = (_Float16)0.f;
        aB[i].x = (_Float16)0.f; aB[i].y = (_Float16)0.f;
        aC[i].x = (_Float16)0.f; aC[i].y = (_Float16)0.f;
        aD[i].x = (_Float16)0.f; aD[i].y = (_Float16)0.f;
    }

    if (start < end) {
        int deg = end - start;
        bool small = (deg <= 128);
        unsigned eix0 = 0, eiy0 = 0, eix1 = 0, eiy1 = 0;
        if (small) {                       // merged edge list into 2x wave regs
            int lc0 = start + lane;       if (lc0 > end - 1) lc0 = end - 1;
            int lc1 = start + 64 + lane;  if (lc1 > end - 1) lc1 = end - 1;
            uint2 ea = einfo2[lc0];
            uint2 eb = einfo2[lc1];       // issues in parallel with ea
            eix0 = ea.x; eiy0 = ea.y;
            eix1 = eb.x; eiy1 = eb.y;
        }

        // chunk load: einfo via dual-bank shuffle (small) or memory;
        // h/t gathers EXEC-MASKED for phantom lanes; w carries inv_s of
        // the edge's owning node (3-select).
        auto LOADC = [&](int e0, uint4& h0, uint4& h1, uint4& t0, uint4& t1,
                         float& w) {
            unsigned ax, ay;
            if (small) {
                int slot = e0 - start + g;           // [0,128) for valid lanes
                unsigned axa = __shfl(eix0, slot & 63);
                unsigned aya = __shfl(eiy0, slot & 63);
                unsigned axb = __shfl(eix1, slot & 63);
                unsigned ayb = __shfl(eiy1, slot & 63);
                ax = (slot < 64) ? axa : axb;
                ay = (slot < 64) ? aya : ayb;
            } else {
                int ec = e0 + g; if (ec > end - 1) ec = end - 1;
                uint2 et = einfo2[ec];
                ax = et.x; ay = et.y;
            }
            int e = e0 + g;
            bool valid = (e < end);
            h0 = make_uint4(0u, 0u, 0u, 0u); h1 = h0; t0 = h0; t1 = h0;
            if (valid) {
                unsigned dn = ax & 0xffffu, rl = ax >> 16;
                const uint4* hp = reinterpret_cast<const uint4*>(fbase + (size_t)dn * 256);
                const uint4* tp = reinterpret_cast<const uint4*>(tbase + (size_t)rl * 256);
                h0 = hp[0]; h1 = hp[1];
                t0 = tp[0]; t1 = tp[1];
            }
            h2 ep = __builtin_bit_cast(h2, ay);
            float er = (float)((L == 0) ? ep.x : ep.y);
            float isv = (e < m1) ? is0 : (e < m2) ? is1 : (e < m3) ? is2 : is3;
            w = valid ? er * isv : 0.f;
        };

        // accumulate one chunk into a target register set
        auto ACC = [&](h2 (&acc)[8], float wf, float cf,
                       const h2 (&hh)[8], const h2 (&tt)[8]) {
            _Float16 wh  = (_Float16)wf;
            _Float16 cfh = (_Float16)cf;
            h2 wv; wv.x = wh;  wv.y = wh;
            h2 cv; cv.x = cfh; cv.y = cfh;
            #pragma unroll
            for (int p = 0; p < 8; ++p) {
                acc[p] = hh[p] * wv + acc[p];    // v_pk_fma_f16
                acc[p] = tt[p] * cv + acc[p];    // v_pk_fma_f16
            }
        };

        auto DOCHUNK = [&](int e0, uint4 h0, uint4 h1, uint4 t0, uint4 t1,
                           float wf) {
            h2 hh[8], tt[8];
            hh[0] = __builtin_bit_cast(h2, h0.x); hh[1] = __builtin_bit_cast(h2, h0.y);
            hh[2] = __builtin_bit_cast(h2, h0.z); hh[3] = __builtin_bit_cast(h2, h0.w);
            hh[4] = __builtin_bit_cast(h2, h1.x); hh[5] = __builtin_bit_cast(h2, h1.y);
            hh[6] = __builtin_bit_cast(h2, h1.z); hh[7] = __builtin_bit_cast(h2, h1.w);
            tt[0] = __builtin_bit_cast(h2, t0.x); tt[1] = __builtin_bit_cast(h2, t0.y);
            tt[2] = __builtin_bit_cast(h2, t0.z); tt[3] = __builtin_bit_cast(h2, t0.w);
            tt[4] = __builtin_bit_cast(h2, t1.x); tt[5] = __builtin_bit_cast(h2, t1.y);
            tt[6] = __builtin_bit_cast(h2, t1.z); tt[7] = __builtin_bit_cast(h2, t1.w);
            float d0 = 0.f, d1 = 0.f;
            #pragma unroll
            for (int p = 0; p < 8; p += 2) {
                d0 = FDOT2(hh[p],     tt[p],     d0);
                d1 = FDOT2(hh[p + 1], tt[p + 1], d1);
            }
            float d = d0 + d1;
            d += __shfl_xor(d, 1);
            d += __shfl_xor(d, 2);
            d += __shfl_xor(d, 4);
            float cf = -2.f * wf * d;

            int realEnd = (e0 + 8 < end) ? (e0 + 8) : end;   // wave-uniform
            // pure-chunk fast paths (wave-uniform branches)
            if (realEnd <= m1)      { ACC(aA, wf, cf, hh, tt); }
            else if (e0 >= m3)      { ACC(aD, wf, cf, hh, tt); }
            else if (e0 >= m1 && realEnd <= m2) { ACC(aB, wf, cf, hh, tt); }
            else if (e0 >= m2 && realEnd <= m3) { ACC(aC, wf, cf, hh, tt); }
            else {
                // straddling chunk: masked ACC into each overlapped set
                int e = e0 + g;
                if (e0 < m1) {
                    bool in = (e < m1);
                    ACC(aA, in ? wf : 0.f, in ? cf : 0.f, hh, tt);
                }
                if (realEnd > m1 && e0 < m2) {
                    bool in = (e >= m1) && (e < m2);
                    ACC(aB, in ? wf : 0.f, in ? cf : 0.f, hh, tt);
                }
                if (realEnd > m2 && e0 < m3) {
                    bool in = (e >= m2) && (e < m3);
                    ACC(aC, in ? wf : 0.f, in ? cf : 0.f, hh, tt);
                }
                if (realEnd > m3) {
                    bool in = (e >= m3);
                    ACC(aD, in ? wf : 0.f, in ? cf : 0.f, hh, tt);
                }
            }
        };

        // depth-2 software pipeline over 8-edge chunks of the MERGED range
        uint4 hA0, hA1, tA0, tA1; float wA;
        uint4 hB0, hB1, tB0, tB1; float wB;
        LOADC(start, hA0, hA1, tA0, tA1, wA);
        int e = start;
        while (true) {
            int e2 = e + 8;
            bool moreB = (e2 < end);
            if (moreB) LOADC(e2, hB0, hB1, tB0, tB1, wB);
            __builtin_amdgcn_sched_barrier(0);
            DOCHUNK(e, hA0, hA1, tA0, tA1, wA);
            if (!moreB) break;
            int e3 = e2 + 8;
            bool moreA = (e3 < end);
            if (moreA) LOADC(e3, hA0, hA1, tA0, tA1, wA);
            __builtin_amdgcn_sched_barrier(0);
            DOCHUNK(e2, hB0, hB1, tB0, tB1, wB);
            e = e3;
            if (!moreA) break;
        }
    }

    // Pair-space halving butterfly + tanh + write, once per node.
    auto FOLDW = [&](h2 (&a2)[8], int node) {
        h2 b1[4];
        #pragma unroll
        for (int k = 0; k < 4; ++k) {
            h2 keep = g0 ? a2[2*k + 1] : a2[2*k];
            h2 send = g0 ? a2[2*k] : a2[2*k + 1];
            unsigned su = __shfl_xor(__builtin_bit_cast(unsigned, send), 8);
            b1[k] = keep + __builtin_bit_cast(h2, su);
        }
        h2 b2[2];
        #pragma unroll
        for (int m = 0; m < 2; ++m) {
            h2 keep = g1 ? b1[2*m + 1] : b1[2*m];
            h2 send = g1 ? b1[2*m] : b1[2*m + 1];
            unsigned su = __shfl_xor(__builtin_bit_cast(unsigned, send), 16);
            b2[m] = keep + __builtin_bit_cast(h2, su);
        }
        h2 c;
        {
            h2 keep = g2 ? b2[1] : b2[0];
            h2 send = g2 ? b2[0] : b2[1];
            unsigned su = __shfl_xor(__builtin_bit_cast(unsigned, send), 32);
            c = keep + __builtin_bit_cast(h2, su);
        }
        float y0 = fast_tanh((float)c.x), y1 = fast_tanh((float)c.y);
        int dimo = 16 * q + 2 * g;
        *reinterpret_cast<float2*>(fout + (size_t)node * OUT_STRIDE + dimo)
            = make_float2(y0, y1);
        if (L == 0) {
            h2 pr; pr.x = (_Float16)y0; pr.y = (_Float16)y1;
            *reinterpret_cast<h2*>(fs_out + (size_t)node * DIM + dimo) = pr;
        }
    };

    FOLDW(aA, n0);
    FOLDW(aB, n0 + 1);
    FOLDW(aC, n0 + 2);
    FOLDW(aD, n0 + 3);
}

// ---------------------------------------------------------------------------
extern "C" void kernel_launch(void* const* d_in, const int* in_sizes, int n_in,
                              void* d_out, int out_size, void* d_ws, size_t ws_size,
                              hipStream_t stream)
{
    const float* features = (const float*)d_in[0];
    const float* rel_emb  = (const float*)d_in[1];
    const int*   adj      = (const int*)d_in[2];   // [2, E]: src | dst
    const int*   r_index  = (const int*)d_in[3];   // [2, E]: arange | rel
    const float* r_val    = (const float*)d_in[4];
    const float* attn_k   = (const float*)d_in[8]; // [DEPTH, D]
    float* out = (float*)d_out;

    const int* src   = adj;
    const int* dst   = adj + N_EDGES;
    const int* relid = r_index + N_EDGES;

    // Workspace carve-up (~33 MB)
    char* base = (char*)d_ws;
    _Float16* rhat = (_Float16*)base;                    // (R+1)*128*2 = 256256 B
    float*    er0  = (float*)(base + 256256);            // 4004 -> pad 4008
    float*    er1  = (float*)(base + 260264);            // 4004 -> pad 4008
    int*      rp   = (int*)(base + 264272);              // 200004 -> pad 200016
    float*    s0   = (float*)(base + 464288);            // 200000
    float*    s1   = (float*)(base + 664288);            // 200000
    uint2*    einfo2 = (uint2*)(base + 864288);          // 6.4 MB
    _Float16* fs0  = (_Float16*)(base + 864288 + (size_t)N_EDGES * 8); // 12.8 MB
    _Float16* fs1  = fs0 + (size_t)N_NODES * DIM;                      // 12.8 MB

    prep_kernel<<<PREP_BLOCKS + RP_BLOCKS, 256, 0, stream>>>(
        rel_emb, attn_k, rhat, er0, er1, src, rp, s0, s1);
    aux_fused_kernel<<<TANH0_BLOCKS + EINFO_BLOCKS, 256, 0, stream>>>(
        features, out, fs0, src, dst, relid, r_val, er0, er1, s0, s1, einfo2);

    // 12500 quad-node waves, 2 per block
    layer_fused_kernel<0><<<(N_NODES / 4 + 1) / 2, 128, 0, stream>>>(
        fs0, out + 1 * DIM, fs1, einfo2, rp, s0, rhat);
    layer_fused_kernel<1><<<(N_NODES / 4 + 1) / 2, 128, 0, stream>>>(
        fs1, out + 2 * DIM, fs0, einfo2, rp, s1, rhat);
}

// Round 18
// 120.522 us; speedup vs baseline: 4.2001x; 4.2001x over previous
//
#include <hip/hip_runtime.h>
#include <hip/hip_bf16.h>
#include <math.h>

// Problem constants (fixed by setup_inputs)
#define N_NODES   50000
#define N_EDGES   800000
#define N_REL     1000
#define DIM       128
#define DEPTH_L   2
#define OUT_STRIDE (DIM * (DEPTH_L + 1))   // 384

#define TANH0_BLOCKS  ((N_NODES * 32) / 256)          // 6250 (exact)
#define EINFO_BLOCKS  ((N_EDGES + 255) / 256)         // 3125 (exact)
#define PREP_BLOCKS   ((N_REL + 1 + 3) / 4)           // 251 (4 relations/block)
#define RP_BLOCKS     ((N_NODES + 1 + 255) / 256)     // 196

typedef _Float16 h2 __attribute__((ext_vector_type(2)));

#if defined(__has_builtin)
#if __has_builtin(__builtin_amdgcn_fdot2)
#define FDOT2(a, b, c) __builtin_amdgcn_fdot2((a), (b), (c), false)
#endif
#endif
#ifndef FDOT2
#define FDOT2(a, b, c) ((c) + (float)(a).x * (float)(b).x + (float)(a).y * (float)(b).y)
#endif

// fast tanh: (e^{2x}-1)/(e^{2x}+1), clamped so exp never overflows.
__device__ __forceinline__ float fast_tanh(float x) {
    float cx = fminf(fmaxf(x, -15.f), 15.f);
    float e = __expf(2.f * cx);
    return (e - 1.f) * __frcp_rn(e + 1.f);
}

// ---------------------------------------------------------------------------
// Kernel 1 (FUSED, partitioned by blockIdx):
//   blocks [0, PREP_BLOCKS): per-relation precompute, 4 relations/block.
//   blocks [PREP_BLOCKS, ..): CSR row pointers (binary search) + s0/s1 zero.
// ---------------------------------------------------------------------------
__global__ __launch_bounds__(256) void prep_kernel(
    const float* __restrict__ rel_emb,
    const float* __restrict__ attn_k,
    _Float16* __restrict__ rhat,
    float* __restrict__ er0, float* __restrict__ er1,
    const int* __restrict__ src, int* __restrict__ rp,
    float* __restrict__ s0, float* __restrict__ s1)
{
    if (blockIdx.x < PREP_BLOCKS) {
        int wid  = threadIdx.x >> 6;
        int lane = threadIdx.x & 63;
        int r = blockIdx.x * 4 + wid;
        if (r > N_REL) return;
        if (r == N_REL) {                   // zero row / unit exp slot
            rhat[(size_t)r * DIM + lane]      = (_Float16)0.f;
            rhat[(size_t)r * DIM + lane + 64] = (_Float16)0.f;
            if (lane == 0) { er0[N_REL] = 1.f; er1[N_REL] = 1.f; }
            return;
        }
        float v0 = rel_emb[r * DIM + lane];
        float v1 = rel_emb[r * DIM + lane + 64];
        float ss = v0 * v0 + v1 * v1;
        #pragma unroll
        for (int o = 32; o >= 1; o >>= 1) ss += __shfl_xor(ss, o);
        float inv = 1.0f / fmaxf(sqrtf(ss), 1e-12f);
        float t0 = v0 * inv, t1 = v1 * inv;
        rhat[(size_t)r * DIM + lane]      = (_Float16)t0;
        rhat[(size_t)r * DIM + lane + 64] = (_Float16)t1;
        #pragma unroll
        for (int l = 0; l < DEPTH_L; ++l) {
            float d = t0 * attn_k[l * DIM + lane] + t1 * attn_k[l * DIM + lane + 64];
            #pragma unroll
            for (int o = 32; o >= 1; o >>= 1) d += __shfl_xor(d, o);
            if (lane == 0) {
                if (l == 0) er0[r] = __expf(d); else er1[r] = __expf(d);
            }
        }
        return;
    }

    int n = (blockIdx.x - PREP_BLOCKS) * 256 + threadIdx.x;
    if (n > N_NODES) return;
    int lo = 0, hi = N_EDGES;
    while (lo < hi) {
        int mid = (lo + hi) >> 1;
        if (src[mid] < n) lo = mid + 1; else hi = mid;
    }
    rp[n] = lo;
    if (n < N_NODES) { s0[n] = 0.f; s1[n] = 0.f; }
}

// ---------------------------------------------------------------------------
// Kernel 2 (FUSED independent aux work, partitioned by blockIdx):
//   blocks [0, TANH0_BLOCKS): out[:,0:128] = tanh(features) + f16 mirror
//   blocks [TANH0_BLOCKS, ..): edge-parallel softmax denominator + einfo2
// ---------------------------------------------------------------------------
__global__ __launch_bounds__(256) void aux_fused_kernel(
    const float* __restrict__ feat, float* __restrict__ out,
    _Float16* __restrict__ fs0,
    const int* __restrict__ src, const int* __restrict__ dst,
    const int* __restrict__ relid, const float* __restrict__ rval,
    const float* __restrict__ er0, const float* __restrict__ er1,
    float* __restrict__ s0, float* __restrict__ s1,
    uint2* __restrict__ einfo2)
{
    if (blockIdx.x < TANH0_BLOCKS) {
        int i = blockIdx.x * 256 + threadIdx.x;      // exactly N*32 threads
        int n = i >> 5;
        int j = i & 31;
        float4 v = reinterpret_cast<const float4*>(feat + (size_t)n * DIM)[j];
        float4 o;
        o.x = fast_tanh(v.x); o.y = fast_tanh(v.y);
        o.z = fast_tanh(v.z); o.w = fast_tanh(v.w);
        reinterpret_cast<float4*>(out + (size_t)n * OUT_STRIDE)[j] = o;
        h2 p0; p0.x = (_Float16)o.x; p0.y = (_Float16)o.y;
        h2 p1; p1.x = (_Float16)o.z; p1.y = (_Float16)o.w;
        uint2 u;
        u.x = __builtin_bit_cast(unsigned, p0);
        u.y = __builtin_bit_cast(unsigned, p1);
        reinterpret_cast<uint2*>(fs0 + (size_t)n * DIM)[j] = u;
        return;
    }

    int e = (blockIdx.x - TANH0_BLOCKS) * 256 + threadIdx.x;
    if (e >= N_EDGES) return;
    int lane = threadIdx.x & 63;
    int sn = src[e];
    int r = (rval[e] == 0.f) ? N_REL : relid[e];
    float x0 = er0[r], x1 = er1[r];

    h2 ep; ep.x = (_Float16)x0; ep.y = (_Float16)x1;
    einfo2[e] = make_uint2((unsigned)dst[e] | ((unsigned)r << 16),
                           __builtin_bit_cast(unsigned, ep));

    // segmented inclusive scan over lanes with equal sn (src is sorted)
    #pragma unroll
    for (int off = 1; off < 64; off <<= 1) {
        float y0 = __shfl_up(x0, off);
        float y1 = __shfl_up(x1, off);
        int   sp = __shfl_up(sn, off);
        if (lane >= off && sp == sn) { x0 += y0; x1 += y1; }
    }
    int snext = __shfl_down(sn, 1);
    bool lastlane = (lane == 63) || (e == N_EDGES - 1) || (snext != sn);
    if (lastlane) {
        atomicAdd(&s0[sn], x0);
        atomicAdd(&s1[sn], x1);
    }
}

// ---------------------------------------------------------------------------
// Kernel 3 (per layer L): FUSED gather + reflect + accumulate, f16 inputs.
// MERGED-RANGE QUAD-NODE WAVES, spill-proofed: all chunk helpers are MACROS
// (no reference-to-array lambda params -> SROA keeps accumulators in VGPRs)
// and __launch_bounds__(128,2) sets a 256-VGPR budget. One wave owns nodes
// 4k..4k+3 (contiguous edges); one head; ~8-chunk depth-2 pipeline with
// sched_barrier(0); exec-masked tail gathers (w=0). 8 lanes/edge.
// ---------------------------------------------------------------------------
template<int L>
__global__ __launch_bounds__(128, 2) void layer_fused_kernel(
    const _Float16* __restrict__ fs_in,   // [N,128] f16
    float* __restrict__ fout,             // column block in d_out
    _Float16* __restrict__ fs_out,        // [N,128] f16 mirror (L==0 only)
    const uint2* __restrict__ einfo2,
    const int* __restrict__ rp,
    const float* __restrict__ s_l,        // [N] softmax denominators
    const _Float16* __restrict__ rhat)    // [(R+1),128] f16
{
    int wid  = threadIdx.x >> 6;
    int lane = threadIdx.x & 63;
    int wave = blockIdx.x * 2 + wid;
    int n0 = wave * 4;
    if (n0 >= N_NODES) return;            // N divisible by 4
    int start = rp[n0], m1 = rp[n0 + 1], m2 = rp[n0 + 2],
        m3 = rp[n0 + 3], end = rp[n0 + 4];

    float is0 = 1.0f / s_l[n0];
    float is1 = 1.0f / s_l[n0 + 1];
    float is2 = 1.0f / s_l[n0 + 2];
    float is3 = 1.0f / s_l[n0 + 3];

    int g = lane >> 3;      // edge slot within chunk (0..7)
    int q = lane & 7;       // dim group: dims [16q, 16q+16)
    const char* fbase = (const char*)fs_in + 32 * q;
    const char* tbase = (const char*)rhat  + 32 * q;
    int g0 = (lane >> 3) & 1, g1 = (lane >> 4) & 1, g2 = (lane >> 5) & 1;

    h2 aA[8], aB[8], aC[8], aD[8];
    #pragma unroll
    for (int i = 0; i < 8; ++i) {
        aA[i].x = (_Float16)0.f; aA[i].y = (_Float16)0.f;
        aB[i].x = (_Float16)0.f; aB[i].y = (_Float16)0.f;
        aC[i].x = (_Float16)0.f; aC[i].y = (_Float16)0.f;
        aD[i].x = (_Float16)0.f; aD[i].y = (_Float16)0.f;
    }

    if (start < end) {
        int deg = end - start;
        bool small = (deg <= 128);
        unsigned eix0 = 0, eiy0 = 0, eix1 = 0, eiy1 = 0;
        if (small) {                       // merged edge list into 2x wave regs
            int lc0 = start + lane;       if (lc0 > end - 1) lc0 = end - 1;
            int lc1 = start + 64 + lane;  if (lc1 > end - 1) lc1 = end - 1;
            uint2 ea = einfo2[lc0];
            uint2 eb = einfo2[lc1];       // issues in parallel with ea
            eix0 = ea.x; eiy0 = ea.y;
            eix1 = eb.x; eiy1 = eb.y;
        }

#define LOADC(E0, H0, H1, T0, T1, W) do {                                     \
    unsigned ax_, ay_;                                                        \
    if (small) {                                                              \
        int slot_ = (E0) - start + g;                                         \
        unsigned axa_ = __shfl(eix0, slot_ & 63);                             \
        unsigned aya_ = __shfl(eiy0, slot_ & 63);                             \
        unsigned axb_ = __shfl(eix1, slot_ & 63);                             \
        unsigned ayb_ = __shfl(eiy1, slot_ & 63);                             \
        ax_ = (slot_ < 64) ? axa_ : axb_;                                     \
        ay_ = (slot_ < 64) ? aya_ : ayb_;                                     \
    } else {                                                                  \
        int ec_ = (E0) + g; if (ec_ > end - 1) ec_ = end - 1;                 \
        uint2 et_ = einfo2[ec_];                                              \
        ax_ = et_.x; ay_ = et_.y;                                             \
    }                                                                         \
    int ee_ = (E0) + g;                                                       \
    bool valid_ = (ee_ < end);                                                \
    H0 = make_uint4(0u, 0u, 0u, 0u); H1 = H0; T0 = H0; T1 = H0;               \
    if (valid_) {                                                             \
        unsigned dn_ = ax_ & 0xffffu, rl_ = ax_ >> 16;                        \
        const uint4* hp_ = reinterpret_cast<const uint4*>(fbase + (size_t)dn_ * 256); \
        const uint4* tp_ = reinterpret_cast<const uint4*>(tbase + (size_t)rl_ * 256); \
        H0 = hp_[0]; H1 = hp_[1];                                             \
        T0 = tp_[0]; T1 = tp_[1];                                             \
    }                                                                         \
    h2 ep_ = __builtin_bit_cast(h2, ay_);                                     \
    float er_ = (float)((L == 0) ? ep_.x : ep_.y);                            \
    float isv_ = (ee_ < m1) ? is0 : (ee_ < m2) ? is1 : (ee_ < m3) ? is2 : is3;\
    W = valid_ ? er_ * isv_ : 0.f;                                            \
} while (0)

#define ACCM(ARR, WF, CF) do {                                                \
    _Float16 wh_ = (_Float16)(WF);                                            \
    _Float16 ch_ = (_Float16)(CF);                                            \
    h2 wv_; wv_.x = wh_; wv_.y = wh_;                                         \
    h2 cv_; cv_.x = ch_; cv_.y = ch_;                                         \
    _Pragma("unroll")                                                         \
    for (int p_ = 0; p_ < 8; ++p_) {                                          \
        ARR[p_] = hh_[p_] * wv_ + ARR[p_];   /* v_pk_fma_f16 */               \
        ARR[p_] = tt_[p_] * cv_ + ARR[p_];   /* v_pk_fma_f16 */               \
    }                                                                         \
} while (0)

#define DOCHUNK(E0, H0, H1, T0, T1, WF) do {                                  \
    h2 hh_[8], tt_[8];                                                        \
    hh_[0] = __builtin_bit_cast(h2, H0.x); hh_[1] = __builtin_bit_cast(h2, H0.y); \
    hh_[2] = __builtin_bit_cast(h2, H0.z); hh_[3] = __builtin_bit_cast(h2, H0.w); \
    hh_[4] = __builtin_bit_cast(h2, H1.x); hh_[5] = __builtin_bit_cast(h2, H1.y); \
    hh_[6] = __builtin_bit_cast(h2, H1.z); hh_[7] = __builtin_bit_cast(h2, H1.w); \
    tt_[0] = __builtin_bit_cast(h2, T0.x); tt_[1] = __builtin_bit_cast(h2, T0.y); \
    tt_[2] = __builtin_bit_cast(h2, T0.z); tt_[3] = __builtin_bit_cast(h2, T0.w); \
    tt_[4] = __builtin_bit_cast(h2, T1.x); tt_[5] = __builtin_bit_cast(h2, T1.y); \
    tt_[6] = __builtin_bit_cast(h2, T1.z); tt_[7] = __builtin_bit_cast(h2, T1.w); \
    float d0_ = 0.f, d1_ = 0.f;                                               \
    _Pragma("unroll")                                                         \
    for (int p_ = 0; p_ < 8; p_ += 2) {                                       \
        d0_ = FDOT2(hh_[p_],     tt_[p_],     d0_);                           \
        d1_ = FDOT2(hh_[p_ + 1], tt_[p_ + 1], d1_);                           \
    }                                                                         \
    float d_ = d0_ + d1_;                                                     \
    d_ += __shfl_xor(d_, 1);                                                  \
    d_ += __shfl_xor(d_, 2);                                                  \
    d_ += __shfl_xor(d_, 4);                                                  \
    float cf_ = -2.f * (WF) * d_;                                             \
    int realEnd_ = ((E0) + 8 < end) ? ((E0) + 8) : end;   /* wave-uniform */  \
    if (realEnd_ <= m1)      { ACCM(aA, (WF), cf_); }                         \
    else if ((E0) >= m3)     { ACCM(aD, (WF), cf_); }                         \
    else if ((E0) >= m1 && realEnd_ <= m2) { ACCM(aB, (WF), cf_); }           \
    else if ((E0) >= m2 && realEnd_ <= m3) { ACCM(aC, (WF), cf_); }           \
    else {                                                                    \
        int ee_ = (E0) + g;                                                   \
        if ((E0) < m1) {                                                      \
            bool in_ = (ee_ < m1);                                            \
            ACCM(aA, in_ ? (WF) : 0.f, in_ ? cf_ : 0.f);                      \
        }                                                                     \
        if (realEnd_ > m1 && (E0) < m2) {                                     \
            bool in_ = (ee_ >= m1) && (ee_ < m2);                             \
            ACCM(aB, in_ ? (WF) : 0.f, in_ ? cf_ : 0.f);                      \
        }                                                                     \
        if (realEnd_ > m2 && (E0) < m3) {                                     \
            bool in_ = (ee_ >= m2) && (ee_ < m3);                             \
            ACCM(aC, in_ ? (WF) : 0.f, in_ ? cf_ : 0.f);                      \
        }                                                                     \
        if (realEnd_ > m3) {                                                  \
            bool in_ = (ee_ >= m3);                                           \
            ACCM(aD, in_ ? (WF) : 0.f, in_ ? cf_ : 0.f);                      \
        }                                                                     \
    }                                                                         \
} while (0)

        // depth-2 software pipeline over 8-edge chunks of the MERGED range
        uint4 hA0, hA1, tA0, tA1; float wA;
        uint4 hB0, hB1, tB0, tB1; float wB;
        LOADC(start, hA0, hA1, tA0, tA1, wA);
        int e = start;
        while (true) {
            int e2 = e + 8;
            bool moreB = (e2 < end);
            if (moreB) LOADC(e2, hB0, hB1, tB0, tB1, wB);
            __builtin_amdgcn_sched_barrier(0);
            DOCHUNK(e, hA0, hA1, tA0, tA1, wA);
            if (!moreB) break;
            int e3 = e2 + 8;
            bool moreA = (e3 < end);
            if (moreA) LOADC(e3, hA0, hA1, tA0, tA1, wA);
            __builtin_amdgcn_sched_barrier(0);
            DOCHUNK(e2, hB0, hB1, tB0, tB1, wB);
            e = e3;
            if (!moreA) break;
        }
#undef LOADC
#undef ACCM
#undef DOCHUNK
    }

    // Pair-space halving butterfly + tanh + write, once per node (macro —
    // arrays referenced textually, static indices only).
#define FOLDW(A2, NODE) do {                                                  \
    h2 b1_[4];                                                                \
    _Pragma("unroll")                                                         \
    for (int k_ = 0; k_ < 4; ++k_) {                                          \
        h2 keep_ = g0 ? A2[2*k_ + 1] : A2[2*k_];                              \
        h2 send_ = g0 ? A2[2*k_] : A2[2*k_ + 1];                              \
        unsigned su_ = __shfl_xor(__builtin_bit_cast(unsigned, send_), 8);    \
        b1_[k_] = keep_ + __builtin_bit_cast(h2, su_);                        \
    }                                                                         \
    h2 b2_[2];                                                                \
    _Pragma("unroll")                                                         \
    for (int m_ = 0; m_ < 2; ++m_) {                                          \
        h2 keep_ = g1 ? b1_[2*m_ + 1] : b1_[2*m_];                            \
        h2 send_ = g1 ? b1_[2*m_] : b1_[2*m_ + 1];                            \
        unsigned su_ = __shfl_xor(__builtin_bit_cast(unsigned, send_), 16);   \
        b2_[m_] = keep_ + __builtin_bit_cast(h2, su_);                        \
    }                                                                         \
    h2 c_;                                                                    \
    {                                                                         \
        h2 keep_ = g2 ? b2_[1] : b2_[0];                                      \
        h2 send_ = g2 ? b2_[0] : b2_[1];                                      \
        unsigned su_ = __shfl_xor(__builtin_bit_cast(unsigned, send_), 32);   \
        c_ = keep_ + __builtin_bit_cast(h2, su_);                             \
    }                                                                         \
    float y0_ = fast_tanh((float)c_.x), y1_ = fast_tanh((float)c_.y);         \
    int dimo_ = 16 * q + 2 * g;                                               \
    *reinterpret_cast<float2*>(fout + (size_t)(NODE) * OUT_STRIDE + dimo_)    \
        = make_float2(y0_, y1_);                                              \
    if (L == 0) {                                                             \
        h2 pr_; pr_.x = (_Float16)y0_; pr_.y = (_Float16)y1_;                 \
        *reinterpret_cast<h2*>(fs_out + (size_t)(NODE) * DIM + dimo_) = pr_;  \
    }                                                                         \
} while (0)

    FOLDW(aA, n0);
    FOLDW(aB, n0 + 1);
    FOLDW(aC, n0 + 2);
    FOLDW(aD, n0 + 3);
#undef FOLDW
}

// ---------------------------------------------------------------------------
extern "C" void kernel_launch(void* const* d_in, const int* in_sizes, int n_in,
                              void* d_out, int out_size, void* d_ws, size_t ws_size,
                              hipStream_t stream)
{
    const float* features = (const float*)d_in[0];
    const float* rel_emb  = (const float*)d_in[1];
    const int*   adj      = (const int*)d_in[2];   // [2, E]: src | dst
    const int*   r_index  = (const int*)d_in[3];   // [2, E]: arange | rel
    const float* r_val    = (const float*)d_in[4];
    const float* attn_k   = (const float*)d_in[8]; // [DEPTH, D]
    float* out = (float*)d_out;

    const int* src   = adj;
    const int* dst   = adj + N_EDGES;
    const int* relid = r_index + N_EDGES;

    // Workspace carve-up (~33 MB)
    char* base = (char*)d_ws;
    _Float16* rhat = (_Float16*)base;                    // (R+1)*128*2 = 256256 B
    float*    er0  = (float*)(base + 256256);            // 4004 -> pad 4008
    float*    er1  = (float*)(base + 260264);            // 4004 -> pad 4008
    int*      rp   = (int*)(base + 264272);              // 200004 -> pad 200016
    float*    s0   = (float*)(base + 464288);            // 200000
    float*    s1   = (float*)(base + 664288);            // 200000
    uint2*    einfo2 = (uint2*)(base + 864288);          // 6.4 MB
    _Float16* fs0  = (_Float16*)(base + 864288 + (size_t)N_EDGES * 8); // 12.8 MB
    _Float16* fs1  = fs0 + (size_t)N_NODES * DIM;                      // 12.8 MB

    prep_kernel<<<PREP_BLOCKS + RP_BLOCKS, 256, 0, stream>>>(
        rel_emb, attn_k, rhat, er0, er1, src, rp, s0, s1);
    aux_fused_kernel<<<TANH0_BLOCKS + EINFO_BLOCKS, 256, 0, stream>>>(
        features, out, fs0, src, dst, relid, r_val, er0, er1, s0, s1, einfo2);

    // 12500 quad-node waves, 2 per block
    layer_fused_kernel<0><<<(N_NODES / 4) / 2, 128, 0, stream>>>(
        fs0, out + 1 * DIM, fs1, einfo2, rp, s0, rhat);
    layer_fused_kernel<1><<<(N_NODES / 4) / 2, 128, 0, stream>>>(
        fs1, out + 2 * DIM, fs0, einfo2, rp, s1, rhat);
}

// Round 19
// 109.367 us; speedup vs baseline: 4.6285x; 1.1020x over previous
//
#include <hip/hip_runtime.h>
#include <hip/hip_bf16.h>
#include <math.h>

// Problem constants (fixed by setup_inputs)
#define N_NODES   50000
#define N_EDGES   800000
#define N_REL     1000
#define DIM       128
#define DEPTH_L   2
#define OUT_STRIDE (DIM * (DEPTH_L + 1))   // 384

#define TANH0_BLOCKS  ((N_NODES * 32) / 256)          // 6250 (exact)
#define EINFO_BLOCKS  ((N_EDGES + 255) / 256)         // 3125 (exact)
#define PREP_BLOCKS   ((N_REL + 1 + 3) / 4)           // 251 (4 relations/block)
#define RP_BLOCKS     ((N_NODES + 1 + 255) / 256)     // 196

typedef _Float16 h2 __attribute__((ext_vector_type(2)));

#if defined(__has_builtin)
#if __has_builtin(__builtin_amdgcn_fdot2)
#define FDOT2(a, b, c) __builtin_amdgcn_fdot2((a), (b), (c), false)
#endif
#endif
#ifndef FDOT2
#define FDOT2(a, b, c) ((c) + (float)(a).x * (float)(b).x + (float)(a).y * (float)(b).y)
#endif

// fast tanh: (e^{2x}-1)/(e^{2x}+1), clamped so exp never overflows.
__device__ __forceinline__ float fast_tanh(float x) {
    float cx = fminf(fmaxf(x, -15.f), 15.f);
    float e = __expf(2.f * cx);
    return (e - 1.f) * __frcp_rn(e + 1.f);
}

// ---------------------------------------------------------------------------
// Kernel 1 (FUSED, partitioned by blockIdx):
//   blocks [0, PREP_BLOCKS): per-relation precompute, 4 relations/block.
//   blocks [PREP_BLOCKS, ..): CSR row pointers (binary search) + s0/s1 zero.
// ---------------------------------------------------------------------------
__global__ __launch_bounds__(256) void prep_kernel(
    const float* __restrict__ rel_emb,
    const float* __restrict__ attn_k,
    _Float16* __restrict__ rhat,
    float* __restrict__ er0, float* __restrict__ er1,
    const int* __restrict__ src, int* __restrict__ rp,
    float* __restrict__ s0, float* __restrict__ s1)
{
    if (blockIdx.x < PREP_BLOCKS) {
        int wid  = threadIdx.x >> 6;
        int lane = threadIdx.x & 63;
        int r = blockIdx.x * 4 + wid;
        if (r > N_REL) return;
        if (r == N_REL) {                   // zero row / unit exp slot
            rhat[(size_t)r * DIM + lane]      = (_Float16)0.f;
            rhat[(size_t)r * DIM + lane + 64] = (_Float16)0.f;
            if (lane == 0) { er0[N_REL] = 1.f; er1[N_REL] = 1.f; }
            return;
        }
        float v0 = rel_emb[r * DIM + lane];
        float v1 = rel_emb[r * DIM + lane + 64];
        float ss = v0 * v0 + v1 * v1;
        #pragma unroll
        for (int o = 32; o >= 1; o >>= 1) ss += __shfl_xor(ss, o);
        float inv = 1.0f / fmaxf(sqrtf(ss), 1e-12f);
        float t0 = v0 * inv, t1 = v1 * inv;
        rhat[(size_t)r * DIM + lane]      = (_Float16)t0;
        rhat[(size_t)r * DIM + lane + 64] = (_Float16)t1;
        #pragma unroll
        for (int l = 0; l < DEPTH_L; ++l) {
            float d = t0 * attn_k[l * DIM + lane] + t1 * attn_k[l * DIM + lane + 64];
            #pragma unroll
            for (int o = 32; o >= 1; o >>= 1) d += __shfl_xor(d, o);
            if (lane == 0) {
                if (l == 0) er0[r] = __expf(d); else er1[r] = __expf(d);
            }
        }
        return;
    }

    int n = (blockIdx.x - PREP_BLOCKS) * 256 + threadIdx.x;
    if (n > N_NODES) return;
    int lo = 0, hi = N_EDGES;
    while (lo < hi) {
        int mid = (lo + hi) >> 1;
        if (src[mid] < n) lo = mid + 1; else hi = mid;
    }
    rp[n] = lo;
    if (n < N_NODES) { s0[n] = 0.f; s1[n] = 0.f; }
}

// ---------------------------------------------------------------------------
// Kernel 2 (FUSED independent aux work, partitioned by blockIdx):
//   blocks [0, TANH0_BLOCKS): out[:,0:128] = tanh(features) + f16 mirror
//   blocks [TANH0_BLOCKS, ..): edge-parallel softmax denominator + einfo2
// ---------------------------------------------------------------------------
__global__ __launch_bounds__(256) void aux_fused_kernel(
    const float* __restrict__ feat, float* __restrict__ out,
    _Float16* __restrict__ fs0,
    const int* __restrict__ src, const int* __restrict__ dst,
    const int* __restrict__ relid, const float* __restrict__ rval,
    const float* __restrict__ er0, const float* __restrict__ er1,
    float* __restrict__ s0, float* __restrict__ s1,
    uint2* __restrict__ einfo2)
{
    if (blockIdx.x < TANH0_BLOCKS) {
        int i = blockIdx.x * 256 + threadIdx.x;      // exactly N*32 threads
        int n = i >> 5;
        int j = i & 31;
        float4 v = reinterpret_cast<const float4*>(feat + (size_t)n * DIM)[j];
        float4 o;
        o.x = fast_tanh(v.x); o.y = fast_tanh(v.y);
        o.z = fast_tanh(v.z); o.w = fast_tanh(v.w);
        reinterpret_cast<float4*>(out + (size_t)n * OUT_STRIDE)[j] = o;
        h2 p0; p0.x = (_Float16)o.x; p0.y = (_Float16)o.y;
        h2 p1; p1.x = (_Float16)o.z; p1.y = (_Float16)o.w;
        uint2 u;
        u.x = __builtin_bit_cast(unsigned, p0);
        u.y = __builtin_bit_cast(unsigned, p1);
        reinterpret_cast<uint2*>(fs0 + (size_t)n * DIM)[j] = u;
        return;
    }

    int e = (blockIdx.x - TANH0_BLOCKS) * 256 + threadIdx.x;
    if (e >= N_EDGES) return;
    int lane = threadIdx.x & 63;
    int sn = src[e];
    int r = (rval[e] == 0.f) ? N_REL : relid[e];
    float x0 = er0[r], x1 = er1[r];

    h2 ep; ep.x = (_Float16)x0; ep.y = (_Float16)x1;
    einfo2[e] = make_uint2((unsigned)dst[e] | ((unsigned)r << 16),
                           __builtin_bit_cast(unsigned, ep));

    // segmented inclusive scan over lanes with equal sn (src is sorted)
    #pragma unroll
    for (int off = 1; off < 64; off <<= 1) {
        float y0 = __shfl_up(x0, off);
        float y1 = __shfl_up(x1, off);
        int   sp = __shfl_up(sn, off);
        if (lane >= off && sp == sn) { x0 += y0; x1 += y1; }
    }
    int snext = __shfl_down(sn, 1);
    bool lastlane = (lane == 63) || (e == N_EDGES - 1) || (snext != sn);
    if (lastlane) {
        atomicAdd(&s0[sn], x0);
        atomicAdd(&s1[sn], x1);
    }
}

// ---------------------------------------------------------------------------
// Kernel 3 (per layer L): FUSED gather + reflect + accumulate, f16 inputs.
// MERGED-RANGE DUAL-NODE WAVES: one wave owns nodes (2k, 2k+1) whose edges
// are CONTIGUOUS [rp[2k], rp[2k+2]) — one rp load, one upfront einfo load,
// ONE chunk pipeline (head pointer-chase amortized over 2 nodes, ~4 chunks).
// Chunk purity vs mid=rp[2k+1] is wave-uniform: pure chunks take a 16-fma
// path into aA or aB; the (at most one) straddling chunk takes a dual pass.
// Depth-2 pipeline + sched_barrier(0); exec-masked tail gathers (w=0).
// 8 lanes/edge; lane owns 16 dims; pair-space fold per node.
// ---------------------------------------------------------------------------
template<int L>
__global__ __launch_bounds__(128) void layer_fused_kernel(
    const _Float16* __restrict__ fs_in,   // [N,128] f16
    float* __restrict__ fout,             // column block in d_out
    _Float16* __restrict__ fs_out,        // [N,128] f16 mirror (L==0 only)
    const uint2* __restrict__ einfo2,
    const int* __restrict__ rp,
    const float* __restrict__ s_l,        // [N] softmax denominators
    const _Float16* __restrict__ rhat)    // [(R+1),128] f16
{
    int wid  = threadIdx.x >> 6;
    int lane = threadIdx.x & 63;
    int wave = blockIdx.x * 2 + wid;
    int n0 = wave * 2;
    if (n0 >= N_NODES) return;
    int n1 = n0 + 1;                      // N even -> always valid
    int start = rp[n0], mid = rp[n0 + 1], end = rp[n0 + 2];

    float is0 = 1.0f / s_l[n0];           // wave-uniform (unused if deg0==0)
    float is1 = 1.0f / s_l[n1];

    int g = lane >> 3;      // edge slot within chunk (0..7)
    int q = lane & 7;       // dim group: dims [16q, 16q+16)
    const char* fbase = (const char*)fs_in + 32 * q;
    const char* tbase = (const char*)rhat  + 32 * q;
    int g0 = (lane >> 3) & 1, g1 = (lane >> 4) & 1, g2 = (lane >> 5) & 1;

    h2 aA[8], aB[8];
    #pragma unroll
    for (int i = 0; i < 8; ++i) {
        aA[i].x = (_Float16)0.f; aA[i].y = (_Float16)0.f;
        aB[i].x = (_Float16)0.f; aB[i].y = (_Float16)0.f;
    }

    if (start < end) {
        int deg = end - start;
        bool small = (deg <= 64);
        unsigned eix = 0, eiy = 0;
        if (small) {                       // whole merged edge list into regs
            int lc = start + lane; if (lc > end - 1) lc = end - 1;
            uint2 et = einfo2[lc];
            eix = et.x; eiy = et.y;
        }

        // chunk load: einfo via shuffle (small) or memory; h/t gathers
        // EXEC-MASKED for phantom lanes; w carries the per-node inv_s.
        auto LOADC = [&](int e0, uint4& h0, uint4& h1, uint4& t0, uint4& t1,
                         float& w) {
            unsigned ax, ay;
            if (small) {
                int slot = e0 - start + g;     // phantom may wrap: harmless (w=0)
                ax = __shfl(eix, slot);
                ay = __shfl(eiy, slot);
            } else {
                int ec = e0 + g; if (ec > end - 1) ec = end - 1;
                uint2 et = einfo2[ec];
                ax = et.x; ay = et.y;
            }
            bool valid = (e0 + g < end);
            h0 = make_uint4(0u, 0u, 0u, 0u); h1 = h0; t0 = h0; t1 = h0;
            if (valid) {
                unsigned dn = ax & 0xffffu, rl = ax >> 16;
                const uint4* hp = reinterpret_cast<const uint4*>(fbase + (size_t)dn * 256);
                const uint4* tp = reinterpret_cast<const uint4*>(tbase + (size_t)rl * 256);
                h0 = hp[0]; h1 = hp[1];
                t0 = tp[0]; t1 = tp[1];
            }
            h2 ep = __builtin_bit_cast(h2, ay);
            float er = (float)((L == 0) ? ep.x : ep.y);
            float isv = (e0 + g >= mid) ? is1 : is0;
            w = valid ? er * isv : 0.f;
        };

        // accumulate one chunk's contribution into a target register set
        auto ACC = [&](h2 (&acc)[8], float wf, float cf,
                       const h2 (&hh)[8], const h2 (&tt)[8]) {
            _Float16 wh  = (_Float16)wf;
            _Float16 cfh = (_Float16)cf;
            h2 wv; wv.x = wh;  wv.y = wh;
            h2 cv; cv.x = cfh; cv.y = cfh;
            #pragma unroll
            for (int p = 0; p < 8; ++p) {
                acc[p] = hh[p] * wv + acc[p];    // v_pk_fma_f16
                acc[p] = tt[p] * cv + acc[p];    // v_pk_fma_f16
            }
        };

        auto DOCHUNK = [&](int e0, uint4 h0, uint4 h1, uint4 t0, uint4 t1,
                           float wf) {
            h2 hh[8], tt[8];
            hh[0] = __builtin_bit_cast(h2, h0.x); hh[1] = __builtin_bit_cast(h2, h0.y);
            hh[2] = __builtin_bit_cast(h2, h0.z); hh[3] = __builtin_bit_cast(h2, h0.w);
            hh[4] = __builtin_bit_cast(h2, h1.x); hh[5] = __builtin_bit_cast(h2, h1.y);
            hh[6] = __builtin_bit_cast(h2, h1.z); hh[7] = __builtin_bit_cast(h2, h1.w);
            tt[0] = __builtin_bit_cast(h2, t0.x); tt[1] = __builtin_bit_cast(h2, t0.y);
            tt[2] = __builtin_bit_cast(h2, t0.z); tt[3] = __builtin_bit_cast(h2, t0.w);
            tt[4] = __builtin_bit_cast(h2, t1.x); tt[5] = __builtin_bit_cast(h2, t1.y);
            tt[6] = __builtin_bit_cast(h2, t1.z); tt[7] = __builtin_bit_cast(h2, t1.w);
            float d0 = 0.f, d1 = 0.f;
            #pragma unroll
            for (int p = 0; p < 8; p += 2) {
                d0 = FDOT2(hh[p],     tt[p],     d0);
                d1 = FDOT2(hh[p + 1], tt[p + 1], d1);
            }
            float d = d0 + d1;
            d += __shfl_xor(d, 1);
            d += __shfl_xor(d, 2);
            d += __shfl_xor(d, 4);
            float cf = -2.f * wf * d;

            int realEnd = (e0 + 8 < end) ? (e0 + 8) : end;   // wave-uniform
            if (realEnd <= mid) {                 // pure node n0
                ACC(aA, wf, cf, hh, tt);
            } else if (e0 >= mid) {               // pure node n1
                ACC(aB, wf, cf, hh, tt);
            } else {                              // straddling chunk (<=1/wave)
                bool ma = (e0 + g < mid);
                float wfa = ma ? wf : 0.f, cfa = ma ? cf : 0.f;
                float wfb = ma ? 0.f : wf, cfb = ma ? 0.f : cf;
                ACC(aA, wfa, cfa, hh, tt);
                ACC(aB, wfb, cfb, hh, tt);
            }
        };

        // depth-2 software pipeline over 8-edge chunks of the MERGED range
        uint4 hA0, hA1, tA0, tA1; float wA;
        uint4 hB0, hB1, tB0, tB1; float wB;
        LOADC(start, hA0, hA1, tA0, tA1, wA);
        int e = start;
        while (true) {
            int e2 = e + 8;
            bool moreB = (e2 < end);
            if (moreB) LOADC(e2, hB0, hB1, tB0, tB1, wB);
            __builtin_amdgcn_sched_barrier(0);
            DOCHUNK(e, hA0, hA1, tA0, tA1, wA);
            if (!moreB) break;
            int e3 = e2 + 8;
            bool moreA = (e3 < end);
            if (moreA) LOADC(e3, hA0, hA1, tA0, tA1, wA);
            __builtin_amdgcn_sched_barrier(0);
            DOCHUNK(e2, hB0, hB1, tB0, tB1, wB);
            e = e3;
            if (!moreA) break;
        }
    }

    // Pair-space halving butterfly + tanh + write, once per node.
    auto FOLDW = [&](h2 (&a2)[8], int node) {
        h2 b1[4];
        #pragma unroll
        for (int k = 0; k < 4; ++k) {
            h2 keep = g0 ? a2[2*k + 1] : a2[2*k];
            h2 send = g0 ? a2[2*k] : a2[2*k + 1];
            unsigned su = __shfl_xor(__builtin_bit_cast(unsigned, send), 8);
            b1[k] = keep + __builtin_bit_cast(h2, su);
        }
        h2 b2[2];
        #pragma unroll
        for (int m = 0; m < 2; ++m) {
            h2 keep = g1 ? b1[2*m + 1] : b1[2*m];
            h2 send = g1 ? b1[2*m] : b1[2*m + 1];
            unsigned su = __shfl_xor(__builtin_bit_cast(unsigned, send), 16);
            b2[m] = keep + __builtin_bit_cast(h2, su);
        }
        h2 c;
        {
            h2 keep = g2 ? b2[1] : b2[0];
            h2 send = g2 ? b2[0] : b2[1];
            unsigned su = __shfl_xor(__builtin_bit_cast(unsigned, send), 32);
            c = keep + __builtin_bit_cast(h2, su);
        }
        float y0 = fast_tanh((float)c.x), y1 = fast_tanh((float)c.y);
        int dimo = 16 * q + 2 * g;
        *reinterpret_cast<float2*>(fout + (size_t)node * OUT_STRIDE + dimo)
            = make_float2(y0, y1);
        if (L == 0) {
            h2 pr; pr.x = (_Float16)y0; pr.y = (_Float16)y1;
            *reinterpret_cast<h2*>(fs_out + (size_t)node * DIM + dimo) = pr;
        }
    };

    FOLDW(aA, n0);
    FOLDW(aB, n1);
}

// ---------------------------------------------------------------------------
extern "C" void kernel_launch(void* const* d_in, const int* in_sizes, int n_in,
                              void* d_out, int out_size, void* d_ws, size_t ws_size,
                              hipStream_t stream)
{
    const float* features = (const float*)d_in[0];
    const float* rel_emb  = (const float*)d_in[1];
    const int*   adj      = (const int*)d_in[2];   // [2, E]: src | dst
    const int*   r_index  = (const int*)d_in[3];   // [2, E]: arange | rel
    const float* r_val    = (const float*)d_in[4];
    const float* attn_k   = (const float*)d_in[8]; // [DEPTH, D]
    float* out = (float*)d_out;

    const int* src   = adj;
    const int* dst   = adj + N_EDGES;
    const int* relid = r_index + N_EDGES;

    // Workspace carve-up (~33 MB)
    char* base = (char*)d_ws;
    _Float16* rhat = (_Float16*)base;                    // (R+1)*128*2 = 256256 B
    float*    er0  = (float*)(base + 256256);            // 4004 -> pad 4008
    float*    er1  = (float*)(base + 260264);            // 4004 -> pad 4008
    int*      rp   = (int*)(base + 264272);              // 200004 -> pad 200016
    float*    s0   = (float*)(base + 464288);            // 200000
    float*    s1   = (float*)(base + 664288);            // 200000
    uint2*    einfo2 = (uint2*)(base + 864288);          // 6.4 MB
    _Float16* fs0  = (_Float16*)(base + 864288 + (size_t)N_EDGES * 8); // 12.8 MB
    _Float16* fs1  = fs0 + (size_t)N_NODES * DIM;                      // 12.8 MB

    prep_kernel<<<PREP_BLOCKS + RP_BLOCKS, 256, 0, stream>>>(
        rel_emb, attn_k, rhat, er0, er1, src, rp, s0, s1);
    aux_fused_kernel<<<TANH0_BLOCKS + EINFO_BLOCKS, 256, 0, stream>>>(
        features, out, fs0, src, dst, relid, r_val, er0, er1, s0, s1, einfo2);

    layer_fused_kernel<0><<<(N_NODES / 2 + 1) / 2, 128, 0, stream>>>(
        fs0, out + 1 * DIM, fs1, einfo2, rp, s0, rhat);
    layer_fused_kernel<1><<<(N_NODES / 2 + 1) / 2, 128, 0, stream>>>(
        fs1, out + 2 * DIM, fs0, einfo2, rp, s1, rhat);
}